// Round 5
// baseline (123.335 us; speedup 1.0000x reference)
//
#include <hip/hip_runtime.h>

#define NROWS 4096
#define DDIM  256
#define MARGIN 0.1f
#define NBLOCKS 256            // 16 x 16 grid of 256x256 tiles, 1 block/CU
#define TILE_H  65536          // halves per K-tile step in a plane pair (2 chunks * 32768)

typedef __attribute__((ext_vector_type(4)))  _Float16 half4;
typedef __attribute__((ext_vector_type(8)))  _Float16 half8;
typedef __attribute__((ext_vector_type(16))) float    floatx16;

// ---------------- Kernel A: diag + packed fp16 hi/lo planes + zero rank ----
// hi=(f16)x, lo=(f16)(x-hi), RNE both. Packed fragment-major layout:
// element (row,k) at ((k>>3)*NROWS + row)*8 + (k&7): 16B = one MFMA fragment
// slice; staging contiguous; LDS fragment reads conflict-free, linear dest.
__global__ __launch_bounds__(256) void prep_kernel(
    const float* __restrict__ v, const float* __restrict__ t,
    float* __restrict__ diag, int* __restrict__ rank,
    _Float16* __restrict__ vhp, _Float16* __restrict__ vlp,
    _Float16* __restrict__ thp, _Float16* __restrict__ tlp) {
  const int wv   = threadIdx.x >> 6;
  const int lane = threadIdx.x & 63;
  const int row  = blockIdx.x * 4 + wv;
  const float4 a = ((const float4*)(v + (size_t)row * DDIM))[lane];
  const float4 b = ((const float4*)(t + (size_t)row * DDIM))[lane];

  half4 ah, al, bh, bl;
  ah.x = (_Float16)a.x; al.x = (_Float16)(a.x - (float)ah.x);
  ah.y = (_Float16)a.y; al.y = (_Float16)(a.y - (float)ah.y);
  ah.z = (_Float16)a.z; al.z = (_Float16)(a.z - (float)ah.z);
  ah.w = (_Float16)a.w; al.w = (_Float16)(a.w - (float)ah.w);
  bh.x = (_Float16)b.x; bl.x = (_Float16)(b.x - (float)bh.x);
  bh.y = (_Float16)b.y; bl.y = (_Float16)(b.y - (float)bh.y);
  bh.z = (_Float16)b.z; bl.z = (_Float16)(b.z - (float)bh.z);
  bh.w = (_Float16)b.w; bl.w = (_Float16)(b.w - (float)bh.w);

  const size_t po = ((size_t)(lane >> 1) * NROWS + row) * 8 + (lane & 1) * 4;
  *(half4*)(vhp + po) = ah;
  *(half4*)(vlp + po) = al;
  *(half4*)(thp + po) = bh;
  *(half4*)(tlp + po) = bl;

  float s = a.x*b.x + a.y*b.y + a.z*b.z + a.w*b.w;
  #pragma unroll
  for (int off = 32; off; off >>= 1) s += __shfl_down(s, off);
  if (lane == 0) { diag[row] = s; rank[row] = 0; }
}

// async global->LDS, 16B per lane, linear LDS dest (wave base + lane*16)
#define GLOAD16(gp, lp) \
  __builtin_amdgcn_global_load_lds( \
      (const __attribute__((address_space(1))) unsigned int*)(gp), \
      (__attribute__((address_space(3))) unsigned int*)(lp), 16, 0, 0)

// ---------------- Kernel B: ring-buffered MFMA GEMM + epilogue -------------
// 256x256 tile, 512 threads, 8 waves (2M x 4N -> 128x64 per wave), BK=16.
// Ring of 4 LDS K-tile buffers (32 KB each, 128 KB total, 1 block/CU),
// depth-3 prefetch, counted vmcnt(8) (never 0 until drain), ONE s_barrier
// per iteration: slot (t+3)&3 == slot (t-1)&3, whose readers all passed
// this iteration's barrier -> single-barrier ring is race-free.
// Term order per acc element: al*bh, ah*bl, ah*bh; k ascending ->
// bit-identical to prior rounds.
__global__ __launch_bounds__(512, 2) void main_kernel(
    const _Float16* __restrict__ vhp, const _Float16* __restrict__ vlp,
    const _Float16* __restrict__ thp, const _Float16* __restrict__ tlp,
    const float* __restrict__ diag, float* __restrict__ pvt,
    float* __restrict__ ptv, int* __restrict__ rank) {
  __shared__ __align__(16) _Float16 ring[4][16384];   // 128 KB
  __shared__ float sdi[256];
  __shared__ float sdj[256];
  __shared__ float red[16];

  const int tid  = threadIdx.x;
  const int w    = tid >> 6;
  const int lane = tid & 63;

  // bijective XCD chunking (256 % 8 == 0): 32 consecutive wgs per XCD
  // = 2 full A-panel rows -> A panels + B reuse L2-local per XCD.
  const int b  = blockIdx.x;
  const int wg = (b & 7) * 32 + (b >> 3);
  const int i0 = (wg >> 4) * 256;
  const int j0 = (wg & 15) * 256;

  if (tid < 256) sdi[tid] = diag[i0 + tid];
  else           sdj[tid - 256] = diag[j0 + tid - 256];
  __syncthreads();   // drains diag loads before counted-vmcnt loop

  // staging: thread -> chunk tid>>8 (0/1), row tid&255; 4 gloads per tile
  // {A-hi, A-lo, B-hi, B-lo}, each 8 KB, LDS dest linear at tid*16B.
  const int schunk = tid >> 8;
  const int srowi  = tid & 255;
  const _Float16* aH = vhp + ((size_t)schunk * NROWS + i0 + srowi) * 8;
  const _Float16* aL = vlp + ((size_t)schunk * NROWS + i0 + srowi) * 8;
  const _Float16* bH = thp + ((size_t)schunk * NROWS + j0 + srowi) * 8;
  const _Float16* bL = tlp + ((size_t)schunk * NROWS + j0 + srowi) * 8;
  const int dsth = tid * 8;   // halves

  // ring[R] layout (halves): [0,4096) A-hi | [4096,8192) A-lo |
  // [8192,12288) B-hi | [12288,16384) B-lo; within region: chunk*2048 + row*8
#define STAGE(R, SOFF) do { \
    GLOAD16(aH + (SOFF), &ring[R][dsth]);          \
    GLOAD16(aL + (SOFF), &ring[R][4096 + dsth]);   \
    GLOAD16(bH + (SOFF), &ring[R][8192 + dsth]);   \
    GLOAD16(bL + (SOFF), &ring[R][12288 + dsth]);  \
  } while (0)

  floatx16 acc[4][2];
  #pragma unroll
  for (int mt = 0; mt < 4; ++mt)
    #pragma unroll
    for (int nt = 0; nt < 2; ++nt)
      #pragma unroll
      for (int r = 0; r < 16; ++r) acc[mt][nt][r] = 0.f;

  const int wm   = w >> 2;            // 0..1 : 128-row band
  const int wn   = w & 3;             // 0..3 : 64-col band
  const int hsel = lane >> 5;         // k-half -> chunk select
  const int aOffH = hsel * 2048 + (wm * 128 + (lane & 31)) * 8;          // + mt*256
  const int bOffH = 8192 + hsel * 2048 + (wn * 64 + (lane & 31)) * 8;    // + nt*256

  // 24 MFMAs: term-outer across 8 independent tiles; per-element order
  // al*bh, ah*bl, ah*bh (unchanged).
#define MFMA_SET(Ah, Al, Bh, Bl)                                                      \
  {                                                                                   \
    _Pragma("unroll") for (int mt = 0; mt < 4; ++mt)                                  \
      _Pragma("unroll") for (int nt = 0; nt < 2; ++nt)                                \
        acc[mt][nt] = __builtin_amdgcn_mfma_f32_32x32x16_f16(Al[mt], Bh[nt], acc[mt][nt], 0, 0, 0); \
    _Pragma("unroll") for (int mt = 0; mt < 4; ++mt)                                  \
      _Pragma("unroll") for (int nt = 0; nt < 2; ++nt)                                \
        acc[mt][nt] = __builtin_amdgcn_mfma_f32_32x32x16_f16(Ah[mt], Bl[nt], acc[mt][nt], 0, 0, 0); \
    _Pragma("unroll") for (int mt = 0; mt < 4; ++mt)                                  \
      _Pragma("unroll") for (int nt = 0; nt < 2; ++nt)                                \
        acc[mt][nt] = __builtin_amdgcn_mfma_f32_32x32x16_f16(Ah[mt], Bh[nt], acc[mt][nt], 0, 0, 0); \
  }

#define COMPUTE(R) do {                                                     \
    const _Float16* P = &ring[R][0];                                        \
    half8 xah[4], xal[4], xbh[2], xbl[2];                                   \
    _Pragma("unroll") for (int nt = 0; nt < 2; ++nt) {                      \
      xbh[nt] = *(const half8*)(P + bOffH + nt * 256);                      \
      xbl[nt] = *(const half8*)(P + 4096 + bOffH + nt * 256);               \
    }                                                                       \
    _Pragma("unroll") for (int mt = 0; mt < 4; ++mt) {                      \
      xah[mt] = *(const half8*)(P + aOffH + mt * 256);                      \
      xal[mt] = *(const half8*)(P + 4096 + aOffH + mt * 256);               \
    }                                                                       \
    __builtin_amdgcn_s_setprio(1);                                          \
    MFMA_SET(xah, xal, xbh, xbl);                                           \
    __builtin_amdgcn_s_setprio(0);                                          \
  } while (0)

  // BODY: wait tile t landed (keep t+1,t+2 in flight) -> barrier ->
  // issue STAGE(t+3) into freed slot -> compute tile t.
#define BODY(R, N, DOSTAGE) do {                                            \
    __builtin_amdgcn_sched_barrier(0);                                      \
    asm volatile("s_waitcnt vmcnt(" #N ")" ::: "memory");                   \
    __builtin_amdgcn_sched_barrier(0);                                      \
    __builtin_amdgcn_s_barrier();                                           \
    __builtin_amdgcn_sched_barrier(0);                                      \
    if (DOSTAGE) { STAGE(((R) + 3) & 3, soff); soff += TILE_H; }            \
    COMPUTE(R);                                                             \
  } while (0)

  // prologue: tiles 0,1,2 in flight (12 vmem ops/thread)
  STAGE(0, 0);
  STAGE(1, TILE_H);
  STAGE(2, (size_t)2 * TILE_H);
  size_t soff = (size_t)3 * TILE_H;

  #pragma unroll 1
  for (int tq = 0; tq < 3; ++tq) {   // t = 0..11, stages tiles 3..14
    BODY(0, 8, true);
    BODY(1, 8, true);
    BODY(2, 8, true);
    BODY(3, 8, true);
  }
  BODY(0, 8, true);    // t=12, stages tile 15
  BODY(1, 8, false);   // t=13
  BODY(2, 4, false);   // t=14
  BODY(3, 0, false);   // t=15

  // ---- epilogue: C/D layout col=lane&31, row=(reg&3)+8*(reg>>2)+4*(lane>>5) ----
  float vt = 0.f, tv = 0.f;
  const int colL = lane & 31;
  #pragma unroll
  for (int mt = 0; mt < 4; ++mt) {
    const int rbase = wm * 128 + mt * 32;
    #pragma unroll
    for (int reg = 0; reg < 16; ++reg) {
      const int r  = (reg & 3) + 8 * (reg >> 2) + 4 * hsel;
      const int gi = i0 + rbase + r;
      const float di = sdi[rbase + r];
      unsigned long long b0 = 0, b1 = 0;
      #pragma unroll
      for (int nt = 0; nt < 2; ++nt) {
        const int c2 = wn * 64 + nt * 32 + colL;
        const int gj = j0 + c2;
        const float sc = acc[mt][nt][reg];
        const float dj = sdj[c2];
        const bool ne = (gi != gj);
        if (ne) {
          vt += fmaxf(0.f, MARGIN - di + sc);
          tv += fmaxf(0.f, MARGIN - dj + sc);
        }
        const unsigned long long bb = __ballot(ne && (sc > di));
        if (nt == 0) b0 = bb; else b1 = bb;
      }
      if (colL == 0) {
        const int cc = hsel ? (int)(__popcll(b0 >> 32) + __popcll(b1 >> 32))
                            : (int)(__popcll(b0 & 0xFFFFFFFFull) + __popcll(b1 & 0xFFFFFFFFull));
        atomicAdd(&rank[gi], cc);
      }
    }
  }
  #pragma unroll
  for (int off = 32; off; off >>= 1) {
    vt += __shfl_down(vt, off);
    tv += __shfl_down(tv, off);
  }
  if (lane == 0) { red[w] = vt; red[8 + w] = tv; }
  __syncthreads();
  if (tid == 0) {
    float av = 0.f, at = 0.f;
    #pragma unroll
    for (int k = 0; k < 8; ++k) { av += red[k]; at += red[8 + k]; }
    pvt[wg] = av;
    ptv[wg] = at;
  }
}

// ---------------- Kernel C: final reduction -> 6 outputs ----------------
__global__ __launch_bounds__(256) void final_kernel(
    const float* __restrict__ pvt, const float* __restrict__ ptv,
    const int* __restrict__ rank, float* __restrict__ out) {
  __shared__ int s1[4], s5[4], s10[4], ssum[4];
  __shared__ float sv[4], st[4];
  const int tid = threadIdx.x;
  int c1 = 0, c5 = 0, c10 = 0, cs = 0;
  for (int i = tid; i < NROWS; i += 256) {
    const int r = rank[i];
    c1  += (r < 1);
    c5  += (r < 5);
    c10 += (r < 10);
    cs  += r;
  }
  float fv = 0.f, ft = 0.f;
  for (int i = tid; i < NBLOCKS; i += 256) { fv += pvt[i]; ft += ptv[i]; }
  #pragma unroll
  for (int off = 32; off; off >>= 1) {
    c1  += __shfl_down(c1, off);
    c5  += __shfl_down(c5, off);
    c10 += __shfl_down(c10, off);
    cs  += __shfl_down(cs, off);
    fv  += __shfl_down(fv, off);
    ft  += __shfl_down(ft, off);
  }
  const int w = tid >> 6;
  if ((tid & 63) == 0) { s1[w] = c1; s5[w] = c5; s10[w] = c10; ssum[w] = cs; sv[w] = fv; st[w] = ft; }
  __syncthreads();
  if (tid == 0) {
    int a1 = 0, a5 = 0, a10 = 0, as = 0; float av = 0.f, at = 0.f;
    for (int k = 0; k < 4; ++k) {
      a1 += s1[k]; a5 += s5[k]; a10 += s10[k]; as += ssum[k];
      av += sv[k]; at += st[k];
    }
    const float denom = 4096.0f * 4095.0f;
    out[0] = av / denom;
    out[1] = at / denom;
    out[2] = a1  / 4096.0f;
    out[3] = a5  / 4096.0f;
    out[4] = a10 / 4096.0f;
    out[5] = (float)as / 4096.0f;
  }
}

extern "C" void kernel_launch(void* const* d_in, const int* in_sizes, int n_in,
                              void* d_out, int out_size, void* d_ws, size_t ws_size,
                              hipStream_t stream) {
  const float* v = (const float*)d_in[0];
  const float* t = (const float*)d_in[1];
  float* out = (float*)d_out;

  char* ws = (char*)d_ws;
  float* diag = (float*)(ws);                       // 16 KB
  int*   rank = (int*)(ws + (16 << 10));            // 16 KB
  float* pvt  = (float*)(ws + (32 << 10));          // 4 KB
  float* ptv  = (float*)(ws + (36 << 10));          // 4 KB
  const size_t PLANE = (size_t)NROWS * DDIM * sizeof(_Float16);  // 2 MB
  _Float16* vhp = (_Float16*)(ws + (64 << 10));
  _Float16* vlp = (_Float16*)(ws + (64 << 10) + PLANE);
  _Float16* thp = (_Float16*)(ws + (64 << 10) + 2 * PLANE);
  _Float16* tlp = (_Float16*)(ws + (64 << 10) + 3 * PLANE);

  hipLaunchKernelGGL(prep_kernel, dim3(NROWS / 4), dim3(256), 0, stream,
                     v, t, diag, rank, vhp, vlp, thp, tlp);
  hipLaunchKernelGGL(main_kernel, dim3(NBLOCKS), dim3(512), 0, stream,
                     vhp, vlp, thp, tlp, diag, pvt, ptv, rank);
  hipLaunchKernelGGL(final_kernel, dim3(1), dim3(256), 0, stream, pvt, ptv, rank, out);
}

// Round 6
// 117.249 us; speedup vs baseline: 1.0519x; 1.0519x over previous
//
#include <hip/hip_runtime.h>

#define NROWS 4096
#define DDIM  256
#define MARGIN 0.1f
#define NBLOCKS 256            // 16 x 16 grid of 256x256 tiles, 1 block/CU
#define TILE_H  65536          // halves per BK=16 K-tile in a plane (2 chunks * 32768)

typedef __attribute__((ext_vector_type(4)))  _Float16 half4;
typedef __attribute__((ext_vector_type(8)))  _Float16 half8;
typedef __attribute__((ext_vector_type(16))) float    floatx16;

// ---------------- Kernel A: diag + packed fp16 hi/lo planes + zero rank ----
// hi=(f16)x, lo=(f16)(x-hi), RNE both. Packed fragment-major layout:
// element (row,k) at ((k>>3)*NROWS + row)*8 + (k&7): 16B = one MFMA fragment
// slice; staging contiguous; LDS fragment reads conflict-free, linear dest.
__global__ __launch_bounds__(256) void prep_kernel(
    const float* __restrict__ v, const float* __restrict__ t,
    float* __restrict__ diag, int* __restrict__ rank,
    _Float16* __restrict__ vhp, _Float16* __restrict__ vlp,
    _Float16* __restrict__ thp, _Float16* __restrict__ tlp) {
  const int wv   = threadIdx.x >> 6;
  const int lane = threadIdx.x & 63;
  const int row  = blockIdx.x * 4 + wv;
  const float4 a = ((const float4*)(v + (size_t)row * DDIM))[lane];
  const float4 b = ((const float4*)(t + (size_t)row * DDIM))[lane];

  half4 ah, al, bh, bl;
  ah.x = (_Float16)a.x; al.x = (_Float16)(a.x - (float)ah.x);
  ah.y = (_Float16)a.y; al.y = (_Float16)(a.y - (float)ah.y);
  ah.z = (_Float16)a.z; al.z = (_Float16)(a.z - (float)ah.z);
  ah.w = (_Float16)a.w; al.w = (_Float16)(a.w - (float)ah.w);
  bh.x = (_Float16)b.x; bl.x = (_Float16)(b.x - (float)bh.x);
  bh.y = (_Float16)b.y; bl.y = (_Float16)(b.y - (float)bh.y);
  bh.z = (_Float16)b.z; bl.z = (_Float16)(b.z - (float)bh.z);
  bh.w = (_Float16)b.w; bl.w = (_Float16)(b.w - (float)bh.w);

  const size_t po = ((size_t)(lane >> 1) * NROWS + row) * 8 + (lane & 1) * 4;
  *(half4*)(vhp + po) = ah;
  *(half4*)(vlp + po) = al;
  *(half4*)(thp + po) = bh;
  *(half4*)(tlp + po) = bl;

  float s = a.x*b.x + a.y*b.y + a.z*b.z + a.w*b.w;
  #pragma unroll
  for (int off = 32; off; off >>= 1) s += __shfl_down(s, off);
  if (lane == 0) { diag[row] = s; rank[row] = 0; }
}

// async global->LDS, 16B per lane, linear LDS dest
#define GLOAD16(gp, lp) \
  __builtin_amdgcn_global_load_lds( \
      (const __attribute__((address_space(1))) unsigned int*)(gp), \
      (__attribute__((address_space(3))) unsigned int*)(lp), 16, 0, 0)

// ---------------- Kernel B: 8-phase-style ring MFMA GEMM + epilogue --------
// 256x256 tile, 512 threads, 8 waves (2M x 4N -> 128x64/wave), BK=16.
// Ring-4 LDS (4 x 32 KB), depth-3 prefetch, counted vmcnt(8) once per K-tile
// (never 0 until drain). Each K-tile = 2 fine phases (m201 template shape):
//   {ds_read subtile || issue 2 gloads} -> barrier -> setprio+12 MFMA -> barrier
// Phase A: A-frags mt0/1 + B-frags (8 b128), stage next-tile A planes.
// Phase B: A-frags mt2/3 (4 b128, B reused in regs), stage B planes.
// Term order per acc element: al*bh, ah*bl, ah*bh; k ascending ->
// bit-identical to prior rounds.
__global__ __launch_bounds__(512, 2) void main_kernel(
    const _Float16* __restrict__ vhp, const _Float16* __restrict__ vlp,
    const _Float16* __restrict__ thp, const _Float16* __restrict__ tlp,
    const float* __restrict__ diag, float* __restrict__ pvt,
    float* __restrict__ ptv, int* __restrict__ rank) {
  __shared__ __align__(16) _Float16 ring[4][16384];   // 128 KB
  __shared__ float sdi[256];
  __shared__ float sdj[256];
  __shared__ float red[16];

  const int tid  = threadIdx.x;
  const int w    = tid >> 6;
  const int lane = tid & 63;

  // bijective XCD chunking (256 % 8 == 0)
  const int b  = blockIdx.x;
  const int wg = (b & 7) * 32 + (b >> 3);
  const int i0 = (wg >> 4) * 256;
  const int j0 = (wg & 15) * 256;

  if (tid < 256) sdi[tid] = diag[i0 + tid];
  else           sdj[tid - 256] = diag[j0 + tid - 256];
  __syncthreads();   // drains diag loads -> clean vmcnt accounting

  // staging: thread -> chunk tid>>8 (0/1), row tid&255; per K-tile 4 gloads
  // {A-hi, A-lo, B-hi, B-lo}, each 8 KB set, LDS dest linear at tid*16B.
  const int schunk = tid >> 8;
  const int srowi  = tid & 255;
  const _Float16* aH = vhp + ((size_t)schunk * NROWS + i0 + srowi) * 8;
  const _Float16* aL = vlp + ((size_t)schunk * NROWS + i0 + srowi) * 8;
  const _Float16* bH = thp + ((size_t)schunk * NROWS + j0 + srowi) * 8;
  const _Float16* bL = tlp + ((size_t)schunk * NROWS + j0 + srowi) * 8;
  const int dsth = tid * 8;   // halves

  // ring slot layout (halves): [0,4096) A-hi | [4096,8192) A-lo |
  // [8192,12288) B-hi | [12288,16384) B-lo; within: chunk*2048 + row*8
#define STAGE_A(R, TN) do { \
    GLOAD16(aH + (size_t)(TN) * TILE_H, &ring[R][dsth]);         \
    GLOAD16(aL + (size_t)(TN) * TILE_H, &ring[R][4096 + dsth]);  \
  } while (0)
#define STAGE_B(R, TN) do { \
    GLOAD16(bH + (size_t)(TN) * TILE_H, &ring[R][8192 + dsth]);  \
    GLOAD16(bL + (size_t)(TN) * TILE_H, &ring[R][12288 + dsth]); \
  } while (0)

  floatx16 acc[4][2];
  #pragma unroll
  for (int mt = 0; mt < 4; ++mt)
    #pragma unroll
    for (int nt = 0; nt < 2; ++nt)
      #pragma unroll
      for (int r = 0; r < 16; ++r) acc[mt][nt][r] = 0.f;

  const int wm   = w >> 2;            // 0..1 : 128-row band
  const int wn   = w & 3;             // 0..3 : 64-col band
  const int hsel = lane >> 5;         // k-half -> chunk select
  const int aBase = hsel * 2048 + (wm * 128 + (lane & 31)) * 8;          // + mt*256
  const int bBase = 8192 + hsel * 2048 + (wn * 64 + (lane & 31)) * 8;    // + nt*256

  half8 Bh[2], Bl[2];   // B frags persist across a tile's two phases

#define MFMA12(Ah, Al, MH)                                                              \
  {                                                                                     \
    _Pragma("unroll") for (int mt = 0; mt < 2; ++mt)                                    \
      _Pragma("unroll") for (int nt = 0; nt < 2; ++nt)                                  \
        acc[(MH)*2+mt][nt] = __builtin_amdgcn_mfma_f32_32x32x16_f16(Al[mt], Bh[nt], acc[(MH)*2+mt][nt], 0, 0, 0); \
    _Pragma("unroll") for (int mt = 0; mt < 2; ++mt)                                    \
      _Pragma("unroll") for (int nt = 0; nt < 2; ++nt)                                  \
        acc[(MH)*2+mt][nt] = __builtin_amdgcn_mfma_f32_32x32x16_f16(Ah[mt], Bl[nt], acc[(MH)*2+mt][nt], 0, 0, 0); \
    _Pragma("unroll") for (int mt = 0; mt < 2; ++mt)                                    \
      _Pragma("unroll") for (int nt = 0; nt < 2; ++nt)                                  \
        acc[(MH)*2+mt][nt] = __builtin_amdgcn_mfma_f32_32x32x16_f16(Ah[mt], Bh[nt], acc[(MH)*2+mt][nt], 0, 0, 0); \
  }

#define PHASE_A(R, TN, DOSTAGE) do {                                    \
    const _Float16* P = &ring[R][0];                                    \
    half8 xah[2], xal[2];                                               \
    _Pragma("unroll") for (int mt = 0; mt < 2; ++mt) {                  \
      xah[mt] = *(const half8*)(P + aBase + mt * 256);                  \
      xal[mt] = *(const half8*)(P + 4096 + aBase + mt * 256);           \
    }                                                                   \
    _Pragma("unroll") for (int nt = 0; nt < 2; ++nt) {                  \
      Bh[nt] = *(const half8*)(P + bBase + nt * 256);                   \
      Bl[nt] = *(const half8*)(P + 4096 + bBase + nt * 256);            \
    }                                                                   \
    if (DOSTAGE) { STAGE_A(((R) + 3) & 3, TN); }                        \
    __builtin_amdgcn_sched_barrier(0);                                  \
    __builtin_amdgcn_s_barrier();                                       \
    __builtin_amdgcn_sched_barrier(0);                                  \
    __builtin_amdgcn_s_setprio(1);                                      \
    MFMA12(xah, xal, 0);                                                \
    __builtin_amdgcn_s_setprio(0);                                      \
    __builtin_amdgcn_sched_barrier(0);                                  \
    __builtin_amdgcn_s_barrier();                                       \
    __builtin_amdgcn_sched_barrier(0);                                  \
  } while (0)

#define PHASE_B(R, TN, DOSTAGE) do {                                    \
    const _Float16* P = &ring[R][0];                                    \
    half8 xah[2], xal[2];                                               \
    _Pragma("unroll") for (int mt = 0; mt < 2; ++mt) {                  \
      xah[mt] = *(const half8*)(P + aBase + (2 + mt) * 256);            \
      xal[mt] = *(const half8*)(P + 4096 + aBase + (2 + mt) * 256);     \
    }                                                                   \
    if (DOSTAGE) { STAGE_B(((R) + 3) & 3, TN); }                        \
    __builtin_amdgcn_sched_barrier(0);                                  \
    __builtin_amdgcn_s_barrier();                                       \
    __builtin_amdgcn_sched_barrier(0);                                  \
    __builtin_amdgcn_s_setprio(1);                                      \
    MFMA12(xah, xal, 1);                                                \
    __builtin_amdgcn_s_setprio(0);                                      \
    __builtin_amdgcn_sched_barrier(0);                                  \
  } while (0)

  // tile-boundary: counted vmcnt validates tile T+1, then barrier
#define ENDTILE(N) do {                                                 \
    asm volatile("s_waitcnt vmcnt(" #N ")" ::: "memory");               \
    __builtin_amdgcn_sched_barrier(0);                                  \
    __builtin_amdgcn_s_barrier();                                       \
    __builtin_amdgcn_sched_barrier(0);                                  \
  } while (0)

  // prologue: tiles 0,1,2 in flight (12 gloads/thread); validate tile 0
  STAGE_A(0, 0); STAGE_B(0, 0);
  STAGE_A(1, 1); STAGE_B(1, 1);
  STAGE_A(2, 2); STAGE_B(2, 2);
  __builtin_amdgcn_sched_barrier(0);
  asm volatile("s_waitcnt vmcnt(8)" ::: "memory");
  __builtin_amdgcn_sched_barrier(0);
  __builtin_amdgcn_s_barrier();
  __builtin_amdgcn_sched_barrier(0);

  // K-tiles T=0..7 (slot = T&3; stage tile T+3 while T<=4)
  PHASE_A(0, 3, true);  PHASE_B(0, 3, true);  ENDTILE(8);
  PHASE_A(1, 4, true);  PHASE_B(1, 4, true);  ENDTILE(8);
  PHASE_A(2, 5, true);  PHASE_B(2, 5, true);  ENDTILE(8);
  PHASE_A(3, 6, true);  PHASE_B(3, 6, true);  ENDTILE(8);
  PHASE_A(0, 7, true);  PHASE_B(0, 7, true);  ENDTILE(8);
  PHASE_A(1, 0, false); PHASE_B(1, 0, false); ENDTILE(4);
  PHASE_A(2, 0, false); PHASE_B(2, 0, false); ENDTILE(0);
  PHASE_A(3, 0, false); PHASE_B(3, 0, false);

  // ---- epilogue: C/D layout col=lane&31, row=(reg&3)+8*(reg>>2)+4*(lane>>5) ----
  float vt = 0.f, tv = 0.f;
  const int colL = lane & 31;
  #pragma unroll
  for (int mt = 0; mt < 4; ++mt) {
    const int rbase = wm * 128 + mt * 32;
    #pragma unroll
    for (int reg = 0; reg < 16; ++reg) {
      const int r  = (reg & 3) + 8 * (reg >> 2) + 4 * hsel;
      const int gi = i0 + rbase + r;
      const float di = sdi[rbase + r];
      unsigned long long b0 = 0, b1 = 0;
      #pragma unroll
      for (int nt = 0; nt < 2; ++nt) {
        const int c2 = wn * 64 + nt * 32 + colL;
        const int gj = j0 + c2;
        const float sc = acc[mt][nt][reg];
        const float dj = sdj[c2];
        const bool ne = (gi != gj);
        if (ne) {
          vt += fmaxf(0.f, MARGIN - di + sc);
          tv += fmaxf(0.f, MARGIN - dj + sc);
        }
        const unsigned long long bb = __ballot(ne && (sc > di));
        if (nt == 0) b0 = bb; else b1 = bb;
      }
      if (colL == 0) {
        const int cc = hsel ? (int)(__popcll(b0 >> 32) + __popcll(b1 >> 32))
                            : (int)(__popcll(b0 & 0xFFFFFFFFull) + __popcll(b1 & 0xFFFFFFFFull));
        atomicAdd(&rank[gi], cc);
      }
    }
  }
  #pragma unroll
  for (int off = 32; off; off >>= 1) {
    vt += __shfl_down(vt, off);
    tv += __shfl_down(tv, off);
  }
  if (lane == 0) { red[w] = vt; red[8 + w] = tv; }
  __syncthreads();
  if (tid == 0) {
    float av = 0.f, at = 0.f;
    #pragma unroll
    for (int k = 0; k < 8; ++k) { av += red[k]; at += red[8 + k]; }
    pvt[wg] = av;
    ptv[wg] = at;
  }
}

// ---------------- Kernel C: final reduction -> 6 outputs ----------------
__global__ __launch_bounds__(256) void final_kernel(
    const float* __restrict__ pvt, const float* __restrict__ ptv,
    const int* __restrict__ rank, float* __restrict__ out) {
  __shared__ int s1[4], s5[4], s10[4], ssum[4];
  __shared__ float sv[4], st[4];
  const int tid = threadIdx.x;
  int c1 = 0, c5 = 0, c10 = 0, cs = 0;
  for (int i = tid; i < NROWS; i += 256) {
    const int r = rank[i];
    c1  += (r < 1);
    c5  += (r < 5);
    c10 += (r < 10);
    cs  += r;
  }
  float fv = 0.f, ft = 0.f;
  for (int i = tid; i < NBLOCKS; i += 256) { fv += pvt[i]; ft += ptv[i]; }
  #pragma unroll
  for (int off = 32; off; off >>= 1) {
    c1  += __shfl_down(c1, off);
    c5  += __shfl_down(c5, off);
    c10 += __shfl_down(c10, off);
    cs  += __shfl_down(cs, off);
    fv  += __shfl_down(fv, off);
    ft  += __shfl_down(ft, off);
  }
  const int w = tid >> 6;
  if ((tid & 63) == 0) { s1[w] = c1; s5[w] = c5; s10[w] = c10; ssum[w] = cs; sv[w] = fv; st[w] = ft; }
  __syncthreads();
  if (tid == 0) {
    int a1 = 0, a5 = 0, a10 = 0, as = 0; float av = 0.f, at = 0.f;
    for (int k = 0; k < 4; ++k) {
      a1 += s1[k]; a5 += s5[k]; a10 += s10[k]; as += ssum[k];
      av += sv[k]; at += st[k];
    }
    const float denom = 4096.0f * 4095.0f;
    out[0] = av / denom;
    out[1] = at / denom;
    out[2] = a1  / 4096.0f;
    out[3] = a5  / 4096.0f;
    out[4] = a10 / 4096.0f;
    out[5] = (float)as / 4096.0f;
  }
}

extern "C" void kernel_launch(void* const* d_in, const int* in_sizes, int n_in,
                              void* d_out, int out_size, void* d_ws, size_t ws_size,
                              hipStream_t stream) {
  const float* v = (const float*)d_in[0];
  const float* t = (const float*)d_in[1];
  float* out = (float*)d_out;

  char* ws = (char*)d_ws;
  float* diag = (float*)(ws);                       // 16 KB
  int*   rank = (int*)(ws + (16 << 10));            // 16 KB
  float* pvt  = (float*)(ws + (32 << 10));          // 4 KB
  float* ptv  = (float*)(ws + (36 << 10));          // 4 KB
  const size_t PLANE = (size_t)NROWS * DDIM * sizeof(_Float16);  // 2 MB
  _Float16* vhp = (_Float16*)(ws + (64 << 10));
  _Float16* vlp = (_Float16*)(ws + (64 << 10) + PLANE);
  _Float16* thp = (_Float16*)(ws + (64 << 10) + 2 * PLANE);
  _Float16* tlp = (_Float16*)(ws + (64 << 10) + 3 * PLANE);

  hipLaunchKernelGGL(prep_kernel, dim3(NROWS / 4), dim3(256), 0, stream,
                     v, t, diag, rank, vhp, vlp, thp, tlp);
  hipLaunchKernelGGL(main_kernel, dim3(NBLOCKS), dim3(512), 0, stream,
                     vhp, vlp, thp, tlp, diag, pvt, ptv, rank);
  hipLaunchKernelGGL(final_kernel, dim3(1), dim3(256), 0, stream, pvt, ptv, rank, out);
}